// Round 1
// baseline (332.037 us; speedup 1.0000x reference)
//
#include <hip/hip_runtime.h>
#include <stdint.h>

// Problem constants
#define M_DIM 32768
#define N_DIM 1024
#define K_DIM 1024

using int32x4 = __attribute__((ext_vector_type(4))) int;
using int32x16 = __attribute__((ext_vector_type(16))) int;
using uint32x4 = __attribute__((ext_vector_type(4))) unsigned int;

__device__ __forceinline__ void gload_lds16(const void* g, void* l) {
  __builtin_amdgcn_global_load_lds(
      (const __attribute__((address_space(1))) void*)g,
      (__attribute__((address_space(3))) void*)l,
      16 /*bytes*/, 0 /*offset*/, 0 /*aux*/);
}

// Quantize 4 floats -> 4 packed int8 in a dword.
// clamp(x*20, -127, 127) via v_med3, then +1.5*2^23 rounds RNE to integer and
// the low mantissa byte IS the int8 two's-complement byte (0x4B400000 + v).
// Equivalence to reference clip(round(x*20)): round/clip commute at the +-127
// boundary; RNE of the exact product vs RNE of the rounded product differs only
// by 1 quant step on half-ulp ties -> output delta <= 8*5e-4 << 0.0625 tol.
__device__ __forceinline__ uint32_t quant4(float4 v) {
  const float S = 20.0f;
  const float MAGIC = 12582912.0f;  // 1.5 * 2^23
  float t0 = __builtin_amdgcn_fmed3f(v.x * S, -127.0f, 127.0f) + MAGIC;
  float t1 = __builtin_amdgcn_fmed3f(v.y * S, -127.0f, 127.0f) + MAGIC;
  float t2 = __builtin_amdgcn_fmed3f(v.z * S, -127.0f, 127.0f) + MAGIC;
  float t3 = __builtin_amdgcn_fmed3f(v.w * S, -127.0f, 127.0f) + MAGIC;
  return (__float_as_uint(t0) & 0xFF) | ((__float_as_uint(t1) & 0xFF) << 8) |
         ((__float_as_uint(t2) & 0xFF) << 16) | (__float_as_uint(t3) << 24);
}

// ---------------- Kernel 1: weight-unpack only ----------------
// HARNESS NOTE: integer inputs arrive as int32 — weight_packed is 524288 int32
// elements, ONE packed byte (0..255) per int32. Byte j of row r: low nibble ->
// w[r][2j], high nibble -> w[r][2j+1]. sext4(v) = ((v&0xF)^8)-8.
__global__ __launch_bounds__(256) void prep_w(const int4* __restrict__ wp,
                                              uint2* __restrict__ w8) {
  const int g = blockIdx.x * 256 + threadIdx.x;  // 4 packed bytes -> 8 int8
  const int4 p = wp[g];
  int w0 = ((p.x & 0xF) ^ 8) - 8;
  int w1 = (((p.x >> 4) & 0xF) ^ 8) - 8;
  int w2 = ((p.y & 0xF) ^ 8) - 8;
  int w3 = (((p.y >> 4) & 0xF) ^ 8) - 8;
  int w4 = ((p.z & 0xF) ^ 8) - 8;
  int w5 = (((p.z >> 4) & 0xF) ^ 8) - 8;
  int w6 = ((p.w & 0xF) ^ 8) - 8;
  int w7 = (((p.w >> 4) & 0xF) ^ 8) - 8;
  uint2 st;
  st.x = (uint32_t)(w0 & 0xFF) | ((uint32_t)(w1 & 0xFF) << 8) |
         ((uint32_t)(w2 & 0xFF) << 16) | ((uint32_t)(w3 & 0xFF) << 24);
  st.y = (uint32_t)(w4 & 0xFF) | ((uint32_t)(w5 & 0xFF) << 8) |
         ((uint32_t)(w6 & 0xFF) << 16) | ((uint32_t)(w7 & 0xFF) << 24);
  w8[g] = st;
}

// ---------------- Kernel 2: fused quantize + int8 GEMM ----------------
// C[m][n] = (sum_k q(x[m][k])*W[n][k]) * 5e-4 + bias[n], f32 out.
// Block = 448 threads:
//   waves 0..3 : consumers — 2x2 grid of 64x64 sub-tiles, mfma_i32_32x32x32_i8.
//                UNCHANGED from the previous kernel; issue NO vm ops in the loop.
//   wave 4     : B-producer — global_load_lds staging of W8, vmcnt(8) discipline.
//   waves 5..6 : A-producers — load x fp32 (1 row/lane), quantize in-register,
//                ds_write_b128 into the swizzled LDS layout. x loads for tile
//                kk+2 are issued one window early (latency hidden across the
//                barrier); quant VALU (~480 cyc/wave/tile) hides under the
//                memory-paced window.
// This removes the A8 intermediate entirely: no 33.5MB write + 33.5MB read, no
// separate 134MB prep pass. x panels are XCD-exclusive (same grid swizzle), so
// the 8 n-blocks sharing a panel hit L2 and HBM-side x traffic stays ~1x.
// LDS layout (both A and B): LDS[r][c16] = G[r][c16 ^ ((r>>1)&3)] (16B chunks).
// 3 buffers; window kk: consumers read buf kk%3, A-producers write buf (kk+1)%3,
// B-producer loads into buf (kk+2)%3 — all distinct mod 3; two-barrier margin
// between any write and the reads of the same buffer.
__global__ __launch_bounds__(448, 4) void gemm_kernel(const float* __restrict__ x,
                                                      const uint8_t* __restrict__ W,
                                                      const float* __restrict__ bias,
                                                      float* __restrict__ out) {
  __shared__ __align__(16) uint8_t sA[3][128 * 64];
  __shared__ __align__(16) uint8_t sB[3][128 * 64];

  const int tid = threadIdx.x;
  const int bx = blockIdx.x;
  const int xcd = bx & 7;
  const int tt = bx >> 3;
  const int m0 = (xcd * 32 + (tt >> 3)) * 128;
  const int n0 = (tt & 7) * 128;

  if (tid >= 320) {
    // ================= A-producer waves (2) =================
    const int lane = tid & 63;
    const int p = (tid - 320) >> 6;  // 0 or 1
    const int r = p * 64 + lane;     // tile row; lane owns the full 64-k row
    const int s = (r >> 1) & 3;      // chunk swizzle for this row
    const float* gx = x + (size_t)(m0 + r) * K_DIM;
    uint32_t wofs[4];
    int gco[4];
#pragma unroll
    for (int i = 0; i < 4; i++) {
      const int c = (lane + i) & 3;  // logical chunk, rotated per lane -> uniform banks
      wofs[i] = (uint32_t)(r * 64 + ((c ^ s) << 4));
      gco[i] = c * 16;               // float offset of chunk within the 64-float tile row
    }
    float4 f[4][4];
    // stage A(0) -> buf0
#pragma unroll
    for (int i = 0; i < 4; i++)
#pragma unroll
      for (int q = 0; q < 4; q++) f[i][q] = ((const float4*)(gx + gco[i]))[q];
#pragma unroll
    for (int i = 0; i < 4; i++) {
      uint32x4 pk;
      pk.x = quant4(f[i][0]); pk.y = quant4(f[i][1]);
      pk.z = quant4(f[i][2]); pk.w = quant4(f[i][3]);
      *(uint32x4*)(&sA[0][0] + wofs[i]) = pk;
    }
    // prefetch x(1) into registers
#pragma unroll
    for (int i = 0; i < 4; i++)
#pragma unroll
      for (int q = 0; q < 4; q++) f[i][q] = ((const float4*)(gx + 64 + gco[i]))[q];
    asm volatile("s_waitcnt lgkmcnt(0)" ::: "memory");  // publish A(0) before barrier 0
    int wbo = 8192;  // buffer byte-offset for tile kk+1
#pragma unroll 1
    for (int kk = 0; kk < 16; kk++) {
      asm volatile("s_barrier" ::: "memory");
      if (kk < 15) {
        // quantize x(kk+1) (loaded last window) -> LDS buf (kk+1)%3
#pragma unroll
        for (int i = 0; i < 4; i++) {
          uint32x4 pk;
          pk.x = quant4(f[i][0]); pk.y = quant4(f[i][1]);
          pk.z = quant4(f[i][2]); pk.w = quant4(f[i][3]);
          *(uint32x4*)(&sA[0][0] + wbo + wofs[i]) = pk;
        }
        asm volatile("s_waitcnt lgkmcnt(0)" ::: "memory");
        wbo = (wbo == 16384) ? 0 : wbo + 8192;
        if (kk < 14) {  // issue x(kk+2) loads; land during next window
          const float* gk = gx + (kk + 2) * 64;
#pragma unroll
          for (int i = 0; i < 4; i++)
#pragma unroll
            for (int q = 0; q < 4; q++) f[i][q] = ((const float4*)(gk + gco[i]))[q];
        }
      }
    }
    // 16 barriers total
  } else if (tid >= 256) {
    // ================= B-producer wave =================
    const int lane = tid - 256;
    const uint8_t* gB[8];
    uint32_t lofs[8];
#pragma unroll
    for (int j = 0; j < 8; j++) {
      const int li = j * 64 + lane;       // chunk id within 512-chunk tile
      const int rr = li >> 2, c = li & 3;
      const int cg = c ^ ((rr >> 1) & 3); // swizzled global 16B chunk
      gB[j] = W + (size_t)(n0 + rr) * K_DIM + cg * 16;
      lofs[j] = (uint32_t)li * 16;
    }
    // Prologue: B(0) -> buf0, B(1) -> buf1 (16 loads in flight)
#pragma unroll
    for (int j = 0; j < 8; j++) gload_lds16(gB[j], &sB[0][0] + lofs[j]);
#pragma unroll
    for (int j = 0; j < 8; j++) gload_lds16(gB[j] + 64, &sB[1][0] + lofs[j]);
    int pbo = 16384;  // buffer byte-offset for tile kk+2
#pragma unroll 1
    for (int kk = 0; kk < 15; kk++) {
      // B(kk) landed (newest 8 — tile kk+1 — may stay in flight), then barrier.
      asm volatile("s_waitcnt vmcnt(8)\n\ts_barrier" ::: "memory");
      if (kk < 14) {
        const int off = (kk + 2) * 64;
#pragma unroll
        for (int j = 0; j < 8; j++) gload_lds16(gB[j] + off, &sB[0][0] + pbo + lofs[j]);
        pbo = (pbo == 16384) ? 0 : pbo + 8192;
      }
    }
    asm volatile("s_waitcnt vmcnt(0)\n\ts_barrier" ::: "memory");  // tile 15 landed
    // 16 barriers total
  } else {
    // ================= consumer waves (unchanged) =================
    const int lane = tid & 63;
    const int wid = tid >> 6;   // 0..3
    const int wm = wid >> 1;    // m-half of 128-tile
    const int wn = wid & 1;     // n-half
    const int rl = lane & 31;   // row/col within 32-tile
    const int hl = lane >> 5;   // k-half selector

    uint32_t offA[2][2], offB[2][2];
#pragma unroll
    for (int mt = 0; mt < 2; mt++)
#pragma unroll
      for (int ks = 0; ks < 2; ks++) {
        const int rA = wm * 64 + mt * 32 + rl;
        const int ccA = (ks * 2 + hl) ^ ((rA >> 1) & 3);
        offA[mt][ks] = (uint32_t)(rA * 64 + ccA * 16);
        const int rB = wn * 64 + mt * 32 + rl;
        const int ccB = (ks * 2 + hl) ^ ((rB >> 1) & 3);
        offB[mt][ks] = (uint32_t)(rB * 64 + ccB * 16);
      }

    int32x16 acc[2][2] = {};
    int cbo = 0;
#pragma unroll 1
    for (int kk = 0; kk < 16; kk++) {
      asm volatile("s_barrier" ::: "memory");  // tile kk visible
      const uint8_t* pA = &sA[0][0] + cbo;
      const uint8_t* pB = &sB[0][0] + cbo;
#pragma unroll
      for (int ks = 0; ks < 2; ks++) {
        int32x4 a0 = *(const int32x4*)(pA + offA[0][ks]);
        int32x4 a1 = *(const int32x4*)(pA + offA[1][ks]);
        int32x4 b0 = *(const int32x4*)(pB + offB[0][ks]);
        int32x4 b1 = *(const int32x4*)(pB + offB[1][ks]);
        acc[0][0] = __builtin_amdgcn_mfma_i32_32x32x32_i8(a0, b0, acc[0][0], 0, 0, 0);
        acc[0][1] = __builtin_amdgcn_mfma_i32_32x32x32_i8(a0, b1, acc[0][1], 0, 0, 0);
        acc[1][0] = __builtin_amdgcn_mfma_i32_32x32x32_i8(a1, b0, acc[1][0], 0, 0, 0);
        acc[1][1] = __builtin_amdgcn_mfma_i32_32x32x32_i8(a1, b1, acc[1][1], 0, 0, 0);
      }
      cbo = (cbo == 16384) ? 0 : cbo + 8192;
    }

    // Epilogue. 32x32 C/D layout: col = lane&31, row = (reg&3) + 8*(reg>>2) + 4*(lane>>5).
    float bv[2];
#pragma unroll
    for (int nt = 0; nt < 2; nt++) bv[nt] = bias[n0 + wn * 64 + nt * 32 + rl];

#pragma unroll
    for (int mt = 0; mt < 2; mt++) {
#pragma unroll
      for (int nt = 0; nt < 2; nt++) {
        const int n_g = n0 + wn * 64 + nt * 32 + rl;
        const int mbase = m0 + wm * 64 + mt * 32 + 4 * hl;
#pragma unroll
        for (int reg = 0; reg < 16; reg++) {
          const int m_g = mbase + (reg & 3) + 8 * (reg >> 2);
          const float v = (float)acc[mt][nt][reg] * 0.0005f + bv[nt];
          __builtin_nontemporal_store(v, &out[(size_t)m_g * N_DIM + n_g]);
        }
      }
    }
  }
}

extern "C" void kernel_launch(void* const* d_in, const int* in_sizes, int n_in,
                              void* d_out, int out_size, void* d_ws, size_t ws_size,
                              hipStream_t stream) {
  const float* x = (const float*)d_in[0];
  const int4* wp = (const int4*)d_in[1];   // int32 per packed byte (harness int rule)
  const float* bias = (const float*)d_in[2];
  float* out = (float*)d_out;

  uint8_t* W8 = (uint8_t*)d_ws;            // 1024*1024 int8 = 1 MiB

  // K1: weight unpack only (512 blocks)
  prep_w<<<512, 256, 0, stream>>>(wp, (uint2*)W8);
  // K2: fused quantize+GEMM. grid = (M/128)*(N/128) = 2048, 448 threads
  gemm_kernel<<<(M_DIM / 128) * (N_DIM / 128), 448, 0, stream>>>(x, W8, bias, out);
}

// Round 2
// 308.585 us; speedup vs baseline: 1.0760x; 1.0760x over previous
//
#include <hip/hip_runtime.h>
#include <stdint.h>

// Problem constants
#define M_DIM 32768
#define N_DIM 1024
#define K_DIM 1024

using int32x4 = __attribute__((ext_vector_type(4))) int;
using int32x16 = __attribute__((ext_vector_type(16))) int;

__device__ __forceinline__ void gload_lds16(const void* g, void* l) {
  __builtin_amdgcn_global_load_lds(
      (const __attribute__((address_space(1))) void*)g,
      (__attribute__((address_space(3))) void*)l,
      16 /*bytes*/, 0 /*offset*/, 0 /*aux*/);
}

// Quantize 4 floats -> 4 packed int8 in a dword.
// clamp(x*20, -127, 127) via v_med3, then +1.5*2^23 rounds RNE to integer and
// the low mantissa byte IS the int8 two's-complement byte (0x4B400000 + v).
__device__ __forceinline__ uint32_t quant4(float4 v) {
  const float S = 20.0f;
  const float MAGIC = 12582912.0f;  // 1.5 * 2^23
  float t0 = __builtin_amdgcn_fmed3f(v.x * S, -127.0f, 127.0f) + MAGIC;
  float t1 = __builtin_amdgcn_fmed3f(v.y * S, -127.0f, 127.0f) + MAGIC;
  float t2 = __builtin_amdgcn_fmed3f(v.z * S, -127.0f, 127.0f) + MAGIC;
  float t3 = __builtin_amdgcn_fmed3f(v.w * S, -127.0f, 127.0f) + MAGIC;
  return (__float_as_uint(t0) & 0xFF) | ((__float_as_uint(t1) & 0xFF) << 8) |
         ((__float_as_uint(t2) & 0xFF) << 16) | (__float_as_uint(t3) << 24);
}

// ---------------- Kernel 1: weight-unpack only ----------------
// HARNESS NOTE: integer inputs arrive as int32 — weight_packed is 524288 int32
// elements, ONE packed byte (0..255) per int32. Byte j of row r: low nibble ->
// w[r][2j], high nibble -> w[r][2j+1]. sext4(v) = ((v&0xF)^8)-8.
__global__ __launch_bounds__(256) void prep_w(const int4* __restrict__ wp,
                                              uint2* __restrict__ w8) {
  const int g = blockIdx.x * 256 + threadIdx.x;  // 4 packed bytes -> 8 int8
  const int4 p = wp[g];
  int w0 = ((p.x & 0xF) ^ 8) - 8;
  int w1 = (((p.x >> 4) & 0xF) ^ 8) - 8;
  int w2 = ((p.y & 0xF) ^ 8) - 8;
  int w3 = (((p.y >> 4) & 0xF) ^ 8) - 8;
  int w4 = ((p.z & 0xF) ^ 8) - 8;
  int w5 = (((p.z >> 4) & 0xF) ^ 8) - 8;
  int w6 = ((p.w & 0xF) ^ 8) - 8;
  int w7 = (((p.w >> 4) & 0xF) ^ 8) - 8;
  uint2 st;
  st.x = (uint32_t)(w0 & 0xFF) | ((uint32_t)(w1 & 0xFF) << 8) |
         ((uint32_t)(w2 & 0xFF) << 16) | ((uint32_t)(w3 & 0xFF) << 24);
  st.y = (uint32_t)(w4 & 0xFF) | ((uint32_t)(w5 & 0xFF) << 8) |
         ((uint32_t)(w6 & 0xFF) << 16) | ((uint32_t)(w7 & 0xFF) << 24);
  w8[g] = st;
}

// ---------------- Kernel 2: fused quantize + int8 GEMM ----------------
// C[m][n] = (sum_k q(x[m][k])*W[n][k]) * 5e-4 + bias[n], f32 out.
// Block = 448 threads:
//   waves 0..3 : consumers — 2x2 grid of 64x64 sub-tiles, mfma_i32_32x32x32_i8;
//                NO vm ops in the loop (vmcnt discipline preserved).
//   wave 4     : B-producer — global_load_lds staging of W8, vmcnt(8) discipline.
//   waves 5..6 : A-producers — COALESCED x loads: one global_load_dwordx4 covers
//                4 complete tile-rows (lanes 0-15 = row r's 256B, 16-31 = r+1, ...)
//                = 16x64B transactions, the coalescing optimum (r1's row-per-lane
//                pattern touched 64 lines/instr -> producer was the critical path).
//                Each lane packs its 4 floats -> 1 dword -> ds_write_b32 at the
//                swizzle-corrected offset (conflict-free: 16 distinct banks per
//                16-lane row-group; 2-way alias across groups is free).
// Pipeline: 3 buffers; window kk: consumers read buf kk%3, A-producers write
// buf (kk+1)%3 (data loaded to regs one window earlier), B-producer loads buf
// (kk+2)%3. 16 barriers per wave. A publishes with lgkmcnt(0) pre-barrier.
// LDS layout (both A and B): LDS[r][c16] = G[r][c16 ^ ((r>>1)&3)] (16B chunks).
__global__ __launch_bounds__(448, 4) void gemm_kernel(const float* __restrict__ x,
                                                      const uint8_t* __restrict__ W,
                                                      const float* __restrict__ bias,
                                                      float* __restrict__ out) {
  __shared__ __align__(16) uint8_t sA[3][128 * 64];
  __shared__ __align__(16) uint8_t sB[3][128 * 64];

  const int tid = threadIdx.x;
  const int bx = blockIdx.x;
  const int xcd = bx & 7;
  const int tt = bx >> 3;
  const int m0 = (xcd * 32 + (tt >> 3)) * 128;
  const int n0 = (tt & 7) * 128;

  if (tid >= 320) {
    // ================= A-producer waves (2) =================
    const int lane = tid & 63;
    const int p = (tid - 320) >> 6;  // 0 or 1: rows [p*64, p*64+64)
    const int rsub = lane >> 4;      // row within each 4-row group
    const int c4 = lane & 15;        // dword index within the 64-float row window
    const int R0 = p * 64 + rsub;    // tile row for j=0
    const float* gx0 = x + (size_t)(m0 + R0) * K_DIM + c4 * 4;
    // LDS byte offset for j=0: row R0, chunk (c4>>2) swizzled by s0=(R0>>1)&3,
    // dword (c4&3). For row R0+4j: s advances by 2j mod 4 -> XOR bit5 when j odd;
    // rows contribute j*256. All fields carry-free, so (base0 + j*256)^((j&1)<<5).
    const int chunk = c4 >> 2;
    const int s0 = (R0 >> 1) & 3;
    const uint32_t base0 =
        (uint32_t)(R0 * 64 + ((chunk ^ s0) << 4) + (c4 & 3) * 4);

    float4 f[16];
    // Tile 0: load (coalesced: 4 rows / instr), quantize -> buf 0.
#pragma unroll
    for (int j = 0; j < 16; j++)
      f[j] = *(const float4*)(gx0 + (size_t)(j * 4) * K_DIM);
#pragma unroll
    for (int j = 0; j < 16; j++) {
      uint32_t ofs = (base0 + (uint32_t)j * 256) ^ ((uint32_t)(j & 1) << 5);
      *(uint32_t*)(&sA[0][0] + ofs) = quant4(f[j]);
    }
    // Prefetch tile 1 into registers.
#pragma unroll
    for (int j = 0; j < 16; j++)
      f[j] = *(const float4*)(gx0 + 64 + (size_t)(j * 4) * K_DIM);
    asm volatile("s_waitcnt lgkmcnt(0)" ::: "memory");  // publish buf 0

    uint32_t wbo = 8192;  // buffer byte-offset for tile kk+1
#pragma unroll 1
    for (int kk = 0; kk < 16; kk++) {
      asm volatile("s_barrier" ::: "memory");
      if (kk < 15) {
        // quantize x(kk+1) (loaded last window) -> LDS buf (kk+1)%3
#pragma unroll
        for (int j = 0; j < 16; j++) {
          uint32_t ofs =
              (wbo + base0 + (uint32_t)j * 256) ^ ((uint32_t)(j & 1) << 5);
          *(uint32_t*)(&sA[0][0] + ofs) = quant4(f[j]);
        }
        asm volatile("s_waitcnt lgkmcnt(0)" ::: "memory");
        wbo = (wbo == 16384) ? 0 : wbo + 8192;
        if (kk < 14) {  // issue x(kk+2) loads; land during next window
          const float* gk = gx0 + (size_t)(kk + 2) * 64;
#pragma unroll
          for (int j = 0; j < 16; j++)
            f[j] = *(const float4*)(gk + (size_t)(j * 4) * K_DIM);
        }
      }
    }
    // 16 barriers total
  } else if (tid >= 256) {
    // ================= B-producer wave =================
    const int lane = tid - 256;
    const uint8_t* gB[8];
    uint32_t lofs[8];
#pragma unroll
    for (int j = 0; j < 8; j++) {
      const int li = j * 64 + lane;       // chunk id within 512-chunk tile
      const int rr = li >> 2, c = li & 3;
      const int cg = c ^ ((rr >> 1) & 3); // swizzled global 16B chunk
      gB[j] = W + (size_t)(n0 + rr) * K_DIM + cg * 16;
      lofs[j] = (uint32_t)li * 16;
    }
    // Prologue: B(0) -> buf0, B(1) -> buf1 (16 loads in flight)
#pragma unroll
    for (int j = 0; j < 8; j++) gload_lds16(gB[j], &sB[0][0] + lofs[j]);
#pragma unroll
    for (int j = 0; j < 8; j++) gload_lds16(gB[j] + 64, &sB[1][0] + lofs[j]);
    int pbo = 16384;  // buffer byte-offset for tile kk+2
#pragma unroll 1
    for (int kk = 0; kk < 15; kk++) {
      // B(kk) landed (newest 8 — tile kk+1 — may stay in flight), then barrier.
      asm volatile("s_waitcnt vmcnt(8)\n\ts_barrier" ::: "memory");
      if (kk < 14) {
        const int off = (kk + 2) * 64;
#pragma unroll
        for (int j = 0; j < 8; j++) gload_lds16(gB[j] + off, &sB[0][0] + pbo + lofs[j]);
        pbo = (pbo == 16384) ? 0 : pbo + 8192;
      }
    }
    asm volatile("s_waitcnt vmcnt(0)\n\ts_barrier" ::: "memory");  // tile 15 landed
    // 16 barriers total
  } else {
    // ================= consumer waves (unchanged) =================
    const int lane = tid & 63;
    const int wid = tid >> 6;   // 0..3
    const int wm = wid >> 1;    // m-half of 128-tile
    const int wn = wid & 1;     // n-half
    const int rl = lane & 31;   // row/col within 32-tile
    const int hl = lane >> 5;   // k-half selector

    uint32_t offA[2][2], offB[2][2];
#pragma unroll
    for (int mt = 0; mt < 2; mt++)
#pragma unroll
      for (int ks = 0; ks < 2; ks++) {
        const int rA = wm * 64 + mt * 32 + rl;
        const int ccA = (ks * 2 + hl) ^ ((rA >> 1) & 3);
        offA[mt][ks] = (uint32_t)(rA * 64 + ccA * 16);
        const int rB = wn * 64 + mt * 32 + rl;
        const int ccB = (ks * 2 + hl) ^ ((rB >> 1) & 3);
        offB[mt][ks] = (uint32_t)(rB * 64 + ccB * 16);
      }

    int32x16 acc[2][2] = {};
    int cbo = 0;
#pragma unroll 1
    for (int kk = 0; kk < 16; kk++) {
      asm volatile("s_barrier" ::: "memory");  // tile kk visible
      const uint8_t* pA = &sA[0][0] + cbo;
      const uint8_t* pB = &sB[0][0] + cbo;
#pragma unroll
      for (int ks = 0; ks < 2; ks++) {
        int32x4 a0 = *(const int32x4*)(pA + offA[0][ks]);
        int32x4 a1 = *(const int32x4*)(pA + offA[1][ks]);
        int32x4 b0 = *(const int32x4*)(pB + offB[0][ks]);
        int32x4 b1 = *(const int32x4*)(pB + offB[1][ks]);
        acc[0][0] = __builtin_amdgcn_mfma_i32_32x32x32_i8(a0, b0, acc[0][0], 0, 0, 0);
        acc[0][1] = __builtin_amdgcn_mfma_i32_32x32x32_i8(a0, b1, acc[0][1], 0, 0, 0);
        acc[1][0] = __builtin_amdgcn_mfma_i32_32x32x32_i8(a1, b0, acc[1][0], 0, 0, 0);
        acc[1][1] = __builtin_amdgcn_mfma_i32_32x32x32_i8(a1, b1, acc[1][1], 0, 0, 0);
      }
      cbo = (cbo == 16384) ? 0 : cbo + 8192;
    }

    // Epilogue. 32x32 C/D layout: col = lane&31, row = (reg&3) + 8*(reg>>2) + 4*(lane>>5).
    float bv[2];
#pragma unroll
    for (int nt = 0; nt < 2; nt++) bv[nt] = bias[n0 + wn * 64 + nt * 32 + rl];

#pragma unroll
    for (int mt = 0; mt < 2; mt++) {
#pragma unroll
      for (int nt = 0; nt < 2; nt++) {
        const int n_g = n0 + wn * 64 + nt * 32 + rl;
        const int mbase = m0 + wm * 64 + mt * 32 + 4 * hl;
#pragma unroll
        for (int reg = 0; reg < 16; reg++) {
          const int m_g = mbase + (reg & 3) + 8 * (reg >> 2);
          const float v = (float)acc[mt][nt][reg] * 0.0005f + bv[nt];
          __builtin_nontemporal_store(v, &out[(size_t)m_g * N_DIM + n_g]);
        }
      }
    }
  }
}

extern "C" void kernel_launch(void* const* d_in, const int* in_sizes, int n_in,
                              void* d_out, int out_size, void* d_ws, size_t ws_size,
                              hipStream_t stream) {
  const float* x = (const float*)d_in[0];
  const int4* wp = (const int4*)d_in[1];   // int32 per packed byte (harness int rule)
  const float* bias = (const float*)d_in[2];
  float* out = (float*)d_out;

  uint8_t* W8 = (uint8_t*)d_ws;            // 1024*1024 int8 = 1 MiB

  // K1: weight unpack only (512 blocks)
  prep_w<<<512, 256, 0, stream>>>(wp, (uint2*)W8);
  // K2: fused quantize+GEMM. grid = (M/128)*(N/128) = 2048, 448 threads
  gemm_kernel<<<(M_DIM / 128) * (N_DIM / 128), 448, 0, stream>>>(x, W8, bias, out);
}

// Round 3
// 267.535 us; speedup vs baseline: 1.2411x; 1.1534x over previous
//
#include <hip/hip_runtime.h>
#include <stdint.h>

// Problem constants
#define M_DIM 32768
#define N_DIM 1024
#define K_DIM 1024

using int32x4 = __attribute__((ext_vector_type(4))) int;
using int32x16 = __attribute__((ext_vector_type(16))) int;

__device__ __forceinline__ void gload_lds16(const void* g, void* l) {
  __builtin_amdgcn_global_load_lds(
      (const __attribute__((address_space(1))) void*)g,
      (__attribute__((address_space(3))) void*)l,
      16 /*bytes*/, 0 /*offset*/, 0 /*aux*/);
}

// ---------------- Kernel 1: fused weight-unpack + activation-quantize ----------------
// Blocks [0,512): unpack int4 weights -> int8 [N, K].
//   HARNESS NOTE: integer inputs arrive as int32 — weight_packed is 524288 int32
//   elements, ONE packed byte (0..255) per int32. Byte j of row r: low nibble ->
//   w[r][2j], high nibble -> w[r][2j+1]. sext4(v) = ((v&0xF)^8)-8.
// Blocks [512, 33280): quantize fp32 x -> int8: clip(rint(x*20), -127, 127).
__global__ __launch_bounds__(256) void prep_kernel(const float* __restrict__ x,
                                                   const int4* __restrict__ wp,
                                                   uint32_t* __restrict__ q,
                                                   uint2* __restrict__ w8) {
  const int bx = blockIdx.x;
  const int tid = threadIdx.x;
  if (bx < 512) {
    const int g = bx * 256 + tid;  // 4 packed bytes -> 8 int8
    const int4 p = wp[g];
    int w0 = ((p.x & 0xF) ^ 8) - 8;
    int w1 = (((p.x >> 4) & 0xF) ^ 8) - 8;
    int w2 = ((p.y & 0xF) ^ 8) - 8;
    int w3 = (((p.y >> 4) & 0xF) ^ 8) - 8;
    int w4 = ((p.z & 0xF) ^ 8) - 8;
    int w5 = (((p.z >> 4) & 0xF) ^ 8) - 8;
    int w6 = ((p.w & 0xF) ^ 8) - 8;
    int w7 = (((p.w >> 4) & 0xF) ^ 8) - 8;
    uint2 st;
    st.x = (uint32_t)(w0 & 0xFF) | ((uint32_t)(w1 & 0xFF) << 8) |
           ((uint32_t)(w2 & 0xFF) << 16) | ((uint32_t)(w3 & 0xFF) << 24);
    st.y = (uint32_t)(w4 & 0xFF) | ((uint32_t)(w5 & 0xFF) << 8) |
           ((uint32_t)(w6 & 0xFF) << 16) | ((uint32_t)(w7 & 0xFF) << 24);
    w8[g] = st;
  } else {
    const int g = (bx - 512) * 256 + tid;  // one float4 per thread
    const float4 v = ((const float4*)x)[g];
    int a0 = (int)rintf(fminf(fmaxf(v.x * 20.0f, -127.0f), 127.0f));
    int a1 = (int)rintf(fminf(fmaxf(v.y * 20.0f, -127.0f), 127.0f));
    int a2 = (int)rintf(fminf(fmaxf(v.z * 20.0f, -127.0f), 127.0f));
    int a3 = (int)rintf(fminf(fmaxf(v.w * 20.0f, -127.0f), 127.0f));
    q[g] = (uint32_t)(a0 & 0xFF) | ((uint32_t)(a1 & 0xFF) << 8) |
           ((uint32_t)(a2 & 0xFF) << 16) | ((uint32_t)(a3 & 0xFF) << 24);
  }
}

// ---------------- Kernel 2: int8 GEMM, producer/consumer wave specialization ----------
// C[m][n] = (sum_k A[m][k]*W[n][k]) * 5e-4 + bias[n], f32 out.
// Block = 320 threads: waves 0..3 = consumers (2x2 grid of 64x64 sub-tiles,
// mfma_i32_32x32x32_i8), wave 4 = producer (global_load_lds staging only).
// 4 LDS buffers (64 KB -> 2 blocks/CU), issue distance 2. Per window the
// producer issues tile kk+2's 16 loads FIRST, then waits vmcnt(16) (= only the
// just-issued 16 may fly) and barriers: tiles kk AND kk+1 are both complete at
// barrier kk. Consumers exploit that to DOUBLE-BUFFER FRAGMENTS: during window
// kk's MFMAs they pre-issue window kk+1's 8 ds_read_b128 (fully unrolled,
// static indices), taking LDS latency off the per-window critical path.
// Consumer waves issue NO vm ops in the loop (vmcnt discipline preserved).
// LDS chunk swizzle: LDS[r][c] = G[r][c ^ ((r>>1)&3)] (16B chunks) -> frag
// ds_read_b128 lands 2-way bank aliasing (free), staging stays lane-contiguous.
// Grid swizzle: bx&7 = XCD (round-robin dispatch) owns m-tiles [32x,32x+32) so
// each A line is L2-filled on exactly one XCD; the 8 n-blocks sharing an m-tile
// are co-resident there -> ~1x A fabric traffic.
__global__ __launch_bounds__(320, 3) void gemm_kernel(const uint8_t* __restrict__ A,
                                                      const uint8_t* __restrict__ W,
                                                      const float* __restrict__ bias,
                                                      float* __restrict__ out) {
  __shared__ uint8_t sA[4][128 * 64];
  __shared__ uint8_t sB[4][128 * 64];

  const int tid = threadIdx.x;
  const int bx = blockIdx.x;
  const int xcd = bx & 7;
  const int tt = bx >> 3;
  const int m0 = (xcd * 32 + (tt >> 3)) * 128;
  const int n0 = (tt & 7) * 128;

  if (tid >= 256) {
    // ================= producer wave =================
    const int lane = tid - 256;
    const uint8_t* gA[8];
    const uint8_t* gB[8];
    uint32_t lofs[8];
#pragma unroll
    for (int j = 0; j < 8; j++) {
      const int li = j * 64 + lane;      // chunk id within 512-chunk tile
      const int r = li >> 2, c = li & 3; // row, LDS slot
      const int cg = c ^ ((r >> 1) & 3); // swizzled global 16B chunk
      gA[j] = A + (size_t)(m0 + r) * K_DIM + cg * 16;
      gB[j] = W + (size_t)(n0 + r) * K_DIM + cg * 16;
      lofs[j] = (uint32_t)li * 16;
    }
    // Prologue: tile 0 -> buf0, tile 1 -> buf1 (32 loads in flight)
#pragma unroll
    for (int j = 0; j < 8; j++) gload_lds16(gA[j], &sA[0][0] + lofs[j]);
#pragma unroll
    for (int j = 0; j < 8; j++) gload_lds16(gB[j], &sB[0][0] + lofs[j]);
#pragma unroll
    for (int j = 0; j < 8; j++) gload_lds16(gA[j] + 64, &sA[1][0] + lofs[j]);
#pragma unroll
    for (int j = 0; j < 8; j++) gload_lds16(gB[j] + 64, &sB[1][0] + lofs[j]);

#pragma unroll 1
    for (int kk = 0; kk < 16; kk++) {
      if (kk < 14) {
        // Issue tile kk+2 BEFORE the wait: vmcnt(16) then proves tiles kk and
        // kk+1 have fully landed when the barrier opens (max 48 in flight <=63).
        const int off = (kk + 2) * 64;
        const uint32_t bo = (uint32_t)((kk + 2) & 3) * 8192;
#pragma unroll
        for (int j = 0; j < 8; j++) gload_lds16(gA[j] + off, &sA[0][0] + bo + lofs[j]);
#pragma unroll
        for (int j = 0; j < 8; j++) gload_lds16(gB[j] + off, &sB[0][0] + bo + lofs[j]);
        asm volatile("s_waitcnt vmcnt(16)\n\ts_barrier" ::: "memory");
      } else {
        asm volatile("s_waitcnt vmcnt(0)\n\ts_barrier" ::: "memory");
      }
    }
    // producer done (16 barriers total, matching consumers)
  } else {
    // ================= consumer waves =================
    const int lane = tid & 63;
    const int wid = tid >> 6;   // 0..3
    const int wm = wid >> 1;    // m-half of 128-tile
    const int wn = wid & 1;     // n-half
    const int rl = lane & 31;   // row/col within 32-tile
    const int hl = lane >> 5;   // k-half selector

    // Fragment LDS byte offsets (A: rows m, B: rows n), swizzle-corrected.
    uint32_t offA[2][2], offB[2][2];
#pragma unroll
    for (int mt = 0; mt < 2; mt++)
#pragma unroll
      for (int ks = 0; ks < 2; ks++) {
        const int rA = wm * 64 + mt * 32 + rl;
        const int ccA = (ks * 2 + hl) ^ ((rA >> 1) & 3);
        offA[mt][ks] = (uint32_t)(rA * 64 + ccA * 16);
        const int rB = wn * 64 + mt * 32 + rl;
        const int ccB = (ks * 2 + hl) ^ ((rB >> 1) & 3);
        offB[mt][ks] = (uint32_t)(rB * 64 + ccB * 16);
      }

    int32x4 fa[2][2][2];  // [set][mt][ks]
    int32x4 fb[2][2][2];  // [set][nt][ks]
    int32x16 acc[2][2] = {};
#pragma unroll
    for (int kk = 0; kk < 16; kk++) {
      asm volatile("s_barrier" ::: "memory");  // tiles kk, kk+1 both resident
      const int cur = kk & 1;                  // static under full unroll
      const uint32_t cb = (uint32_t)(kk & 3) * 8192;
      const uint32_t nb = (uint32_t)((kk + 1) & 3) * 8192;
      if (kk == 0) {
#pragma unroll
        for (int mt = 0; mt < 2; mt++)
#pragma unroll
          for (int ks = 0; ks < 2; ks++) {
            fa[0][mt][ks] = *(const int32x4*)(&sA[0][0] + cb + offA[mt][ks]);
            fb[0][mt][ks] = *(const int32x4*)(&sB[0][0] + cb + offB[mt][ks]);
          }
      }
      if (kk < 15) {  // pre-read next window's fragments (buf kk+1 is complete)
#pragma unroll
        for (int mt = 0; mt < 2; mt++)
#pragma unroll
          for (int ks = 0; ks < 2; ks++) {
            fa[cur ^ 1][mt][ks] = *(const int32x4*)(&sA[0][0] + nb + offA[mt][ks]);
            fb[cur ^ 1][mt][ks] = *(const int32x4*)(&sB[0][0] + nb + offB[mt][ks]);
          }
      }
#pragma unroll
      for (int ks = 0; ks < 2; ks++) {
        acc[0][0] = __builtin_amdgcn_mfma_i32_32x32x32_i8(fa[cur][0][ks], fb[cur][0][ks], acc[0][0], 0, 0, 0);
        acc[0][1] = __builtin_amdgcn_mfma_i32_32x32x32_i8(fa[cur][0][ks], fb[cur][1][ks], acc[0][1], 0, 0, 0);
        acc[1][0] = __builtin_amdgcn_mfma_i32_32x32x32_i8(fa[cur][1][ks], fb[cur][0][ks], acc[1][0], 0, 0, 0);
        acc[1][1] = __builtin_amdgcn_mfma_i32_32x32x32_i8(fa[cur][1][ks], fb[cur][1][ks], acc[1][1], 0, 0, 0);
      }
    }

    // Epilogue. 32x32 C/D layout: col = lane&31, row = (reg&3) + 8*(reg>>2) + 4*(lane>>5).
    float bv[2];
#pragma unroll
    for (int nt = 0; nt < 2; nt++) bv[nt] = bias[n0 + wn * 64 + nt * 32 + rl];

#pragma unroll
    for (int mt = 0; mt < 2; mt++) {
#pragma unroll
      for (int nt = 0; nt < 2; nt++) {
        const int n_g = n0 + wn * 64 + nt * 32 + rl;
        const int mbase = m0 + wm * 64 + mt * 32 + 4 * hl;
#pragma unroll
        for (int reg = 0; reg < 16; reg++) {
          const int m_g = mbase + (reg & 3) + 8 * (reg >> 2);
          const float v = (float)acc[mt][nt][reg] * 0.0005f + bv[nt];
          // lanes 0..31 cover 32 consecutive n -> full 128B lines; write-once data.
          __builtin_nontemporal_store(v, &out[(size_t)m_g * N_DIM + n_g]);
        }
      }
    }
  }
}

extern "C" void kernel_launch(void* const* d_in, const int* in_sizes, int n_in,
                              void* d_out, int out_size, void* d_ws, size_t ws_size,
                              hipStream_t stream) {
  const float* x = (const float*)d_in[0];
  const int4* wp = (const int4*)d_in[1];   // int32 per packed byte (harness int rule)
  const float* bias = (const float*)d_in[2];
  float* out = (float*)d_out;

  uint8_t* A8 = (uint8_t*)d_ws;                       // 32768*1024 int8 = 32 MiB
  uint8_t* W8 = A8 + (size_t)M_DIM * K_DIM;           // 1024*1024 int8 = 1 MiB

  // K1: fused unpack (512 blocks) + quantize (32768 blocks)
  prep_kernel<<<512 + (M_DIM * K_DIM) / (4 * 256), 256, 0, stream>>>(
      x, wp, (uint32_t*)A8, (uint2*)W8);
  // K2: GEMM. grid = (M/128)*(N/128) = 2048, 320 threads (4 consumer + 1 producer waves)
  gemm_kernel<<<(M_DIM / 128) * (N_DIM / 128), 320, 0, stream>>>(A8, W8, bias, out);
}